// Round 10
// baseline (404.915 us; speedup 1.0000x reference)
//
#include <hip/hip_runtime.h>
#include <hip/hip_bf16.h>

#define B_   2
#define S_   2048
#define H_   16
#define HD_  128
#define D_   2048
#define BS_  4096
#define SCALE_ 0.08838834764831845f   // 1/sqrt(128), applied in QKV epilogue (t==0)

typedef __hip_bfloat16 bf16;
typedef float f32x4 __attribute__((ext_vector_type(4)));
typedef __bf16 bf16x8 __attribute__((ext_vector_type(8)));
typedef unsigned short u16x8 __attribute__((ext_vector_type(8)));
typedef unsigned short u16x4 __attribute__((ext_vector_type(4)));

static __device__ __forceinline__ unsigned short f2bf_u(float f) {
  bf16 h = __float2bfloat16(f);
  return __builtin_bit_cast(unsigned short, h);
}
static __device__ __forceinline__ void load_lds16(const void* g, void* l) {
  __builtin_amdgcn_global_load_lds((const __attribute__((address_space(1))) void*)g,
                                   (__attribute__((address_space(3))) void*)l, 16, 0, 0);
}

// ---------------- fp32 -> bf16 convert, 8 elems/thread ----------------
__global__ __launch_bounds__(256) void k_convert(const float* __restrict__ src,
                                                 bf16* __restrict__ dst) {
  const size_t i = ((size_t)blockIdx.x * 256 + threadIdx.x) * 8;
  const float4 a = *(const float4*)(src + i);
  const float4 b = *(const float4*)(src + i + 4);
  u16x8 o;
  o[0] = f2bf_u(a.x); o[1] = f2bf_u(a.y); o[2] = f2bf_u(a.z); o[3] = f2bf_u(a.w);
  o[4] = f2bf_u(b.x); o[5] = f2bf_u(b.y); o[6] = f2bf_u(b.z); o[7] = f2bf_u(b.w);
  *(u16x8*)(dst + i) = o;
}

// ---------- tiled transpose [2048][2048] fp32 -> bf16, one z-slice each ----------
__global__ __launch_bounds__(256) void k_transpose(const float* __restrict__ src0,
                                                   bf16* __restrict__ dst0) {
  const int z = blockIdx.z;
  const float* src = src0 + (size_t)z * D_ * D_;
  bf16* dst = dst0 + (size_t)z * D_ * D_;
  __shared__ float tile[64][65];
  const int t = threadIdx.x;
  const int x0 = blockIdx.x * 64, y0 = blockIdx.y * 64;
#pragma unroll
  for (int i = 0; i < 16; ++i) {
    int idx = t + i * 256, r = idx >> 6, c = idx & 63;
    tile[r][c] = src[(size_t)(y0 + r) * D_ + x0 + c];
  }
  __syncthreads();
#pragma unroll
  for (int i = 0; i < 16; ++i) {
    int idx = t + i * 256, c = idx >> 6, r = idx & 63;
    dst[(size_t)(x0 + c) * D_ + y0 + r] = __float2bfloat16(tile[r][c]);
  }
}

// ---------------- RoPE cos/sin tables [S][64] ----------------
__global__ __launch_bounds__(256) void k_rope_tables(float* __restrict__ cost,
                                                     float* __restrict__ sint) {
  const int idx = blockIdx.x * 256 + threadIdx.x;   // S_*64 total
  const int s = idx >> 6, d = idx & 63;
  const float inv = expf(-(float)d * (9.210340371976184f / 64.f)); // 10000^(-d/64)
  const float ang = (float)s * inv;
  cost[idx] = cosf(ang);
  sint[idx] = sinf(ang);
}

// ============ 128x256 GEMM, BK=32, 3-deep pipeline, counted vmcnt, 2 blocks/CU ============
// (unchanged from round 9 — see comments there)
template <int MODE>
__global__ __launch_bounds__(512, 4) void k_gemm_p(const bf16* __restrict__ A,
                                                   const bf16* __restrict__ Bt,
                                                   float* __restrict__ Cf,
                                                   bf16* __restrict__ qb,
                                                   bf16* __restrict__ kb,
                                                   bf16* __restrict__ vt,
                                                   const float* __restrict__ cost,
                                                   const float* __restrict__ sint) {
  extern __shared__ __align__(16) char smem[];   // 73728 bytes
  const int tid = threadIdx.x;
  const int w = tid >> 6, lane = tid & 63;
  const int wm = w >> 2, wn = w & 3;
  const int lr = lane & 15, lg = lane >> 4;
  const int brow = blockIdx.x * 128, bcol = blockIdx.y * 256;

  f32x4 acc[4][4] = {};

  auto stage = [&](int kt, int buf) {
    char* base = smem + buf * 24576;
    {  // A tile 128x32 (8KB): 1 load/thread
      const int row = tid >> 2, su = tid & 3;
      const int up = su ^ ((row >> 1) & 3);
      load_lds16(A + (size_t)(brow + row) * D_ + kt * 32 + up * 8, base + w * 1024);
    }
#pragma unroll
    for (int i = 0; i < 2; ++i) {  // B tile 256x32 (16KB): 2 loads/thread
      const int slot = i * 512 + tid;
      const int row = slot >> 2, su = slot & 3;
      const int up = su ^ ((row >> 1) & 3);
      load_lds16(Bt + (size_t)(bcol + row) * D_ + kt * 32 + up * 8,
                 base + 8192 + i * 8192 + w * 1024);
    }
  };

  const int NKT = D_ / 32;                       // 64
  stage(0, 0); stage(1, 1);                      // 6 loads/thread in flight
  int bs = 0;                                    // kt % 3
  for (int kt = 0; kt < NKT; ++kt) {
    if (kt < NKT - 1) asm volatile("s_waitcnt vmcnt(3)" ::: "memory");
    else              asm volatile("s_waitcnt vmcnt(0)" ::: "memory");
    __builtin_amdgcn_s_barrier();                // raw: prefetch loads stay in flight
    __builtin_amdgcn_sched_barrier(0);
    if (kt + 2 < NKT) {
      int sb = bs + 2; if (sb >= 3) sb -= 3;
      stage(kt + 2, sb);
    }

    const char* base = smem + bs * 24576;
    bf16x8 af[4], bf4[4];
#pragma unroll
    for (int q = 0; q < 4; ++q) {
      const int r = wm * 64 + q * 16 + lr;
      af[q] = *(const bf16x8*)(base + r * 64 + ((lg ^ ((r >> 1) & 3)) * 16));
    }
#pragma unroll
    for (int nf = 0; nf < 4; ++nf) {
      const int r = wn * 64 + nf * 16 + lr;
      bf4[nf] = *(const bf16x8*)(base + 8192 + r * 64 + ((lg ^ ((r >> 1) & 3)) * 16));
    }
    __builtin_amdgcn_s_setprio(1);
#pragma unroll
    for (int q = 0; q < 4; ++q)
#pragma unroll
      for (int nf = 0; nf < 4; ++nf)
        acc[q][nf] = __builtin_amdgcn_mfma_f32_16x16x32_bf16(af[q], bf4[nf], acc[q][nf], 0, 0, 0);
    __builtin_amdgcn_s_setprio(0);
    bs = (bs == 2) ? 0 : bs + 1;
  }

  if (MODE == 1) {
#pragma unroll
    for (int mf = 0; mf < 4; ++mf)
#pragma unroll
      for (int nf = 0; nf < 4; ++nf) {
        const int col = bcol + wn * 64 + nf * 16 + lr;
#pragma unroll
        for (int j = 0; j < 4; ++j) {
          const int row = brow + wm * 64 + mf * 16 + lg * 4 + j;
          Cf[(size_t)row * D_ + col] = acc[mf][nf][j];
        }
      }
  } else {
    const int t = bcol >> 11;                     // block-uniform (256 | 2048)
#pragma unroll
    for (int mf = 0; mf < 4; ++mf)
#pragma unroll
      for (int nf = 0; nf < 4; ++nf) {
        const int col = bcol + wn * 64 + nf * 16 + lr;
        const int h = (col >> 7) & (H_ - 1), mm = col & (HD_ - 1);
        if (t == 2) {
          const int row0 = brow + wm * 64 + mf * 16 + lg * 4;
          const int b = row0 >> 11, s0 = row0 & (S_ - 1);
          u16x4 pk;
#pragma unroll
          for (int j = 0; j < 4; ++j) pk[j] = f2bf_u(acc[mf][nf][j]);
          *(u16x4*)(vt + ((size_t)(b * H_ + h) * HD_ + mm) * S_ + s0) = pk;
        } else {
          const int i2 = mm >> 1;
          const bool odd = mm & 1;
#pragma unroll
          for (int j = 0; j < 4; ++j) {
            const int row = brow + wm * 64 + mf * 16 + lg * 4 + j;
            const int b = row >> 11, s = row & (S_ - 1);
            const float val = acc[mf][nf][j];
            const float part = __shfl_xor(val, 1, 64);   // col parity == lane parity
            const float c = cost[s * 64 + i2];
            const float sn = sint[s * 64 + i2];
            float o = odd ? (part * sn + val * c) : (val * c - part * sn);
            if (t == 0) o *= SCALE_;
            const int om = odd ? (64 + i2) : i2;
            bf16* dst = (t == 1) ? kb : qb;
            dst[((size_t)(b * H_ + h) * S_ + s) * HD_ + om] = __float2bfloat16(o);
          }
        }
      }
  }
}

// ---------------- flash attention: QBLK=128, K-only LDS dbuf, V direct from L2/L3 ----------------
// grid (16, B*H), complementary qt remap (round-5 load balance). Per iter: shared-kf QK^T for
// both row groups; A/B softmax in SEPARATE Ps slots (independent chains -> ILP); joint PV
// sharing each V fragment (16 global 16B reads/iter instead of 32 LDS reads + staging).
// Last tile is fully masked for group A (kcol > r, diag not in range, m_run already finite)
// -> skip A's QK^T half + softmax + PV there (exact, not approximate).
__global__ __launch_bounds__(256, 2) void k_attn(const bf16* __restrict__ qb,
                                                 const bf16* __restrict__ kb,
                                                 const bf16* __restrict__ vt,
                                                 const int* __restrict__ mask,
                                                 bf16* __restrict__ attn_b) {
  const int tid = threadIdx.x, w = tid >> 6, lane = tid & 63;
  const int lr = lane & 15, lg = lane >> 4;
  const int qt = (blockIdx.y < 16) ? ((int)gridDim.x - 1 - (int)blockIdx.x)
                                   : (int)blockIdx.x;   // complementary pairing
  const int q0 = qt * 128;
  const int bh = blockIdx.y;
  const int b = bh >> 4, h = bh & (H_ - 1);
  const bf16* qp = qb + (size_t)bh * S_ * HD_;
  const bf16* kp = kb + (size_t)bh * S_ * HD_;
  const bf16* vp = vt + (size_t)bh * HD_ * S_;
  __shared__ __align__(16) bf16 Ks[2][64 * 128];   // 2 x 16 KB, XOR-swizzled rows
  __shared__ __align__(16) bf16 Ps[4][2][16][80];  // per-wave, PER-GROUP P tile (20 KB)

  // Q fragments for both row groups (q pre-scaled by 1/sqrt(d) in GEMM epilogue)
  const int qrowA = q0 + w * 16 + lr;
  bf16x8 qfA[4], qfB[4];
#pragma unroll
  for (int ks = 0; ks < 4; ++ks) {
    qfA[ks] = *(const bf16x8*)(qp + (size_t)qrowA * HD_ + ks * 32 + lg * 8);
    qfB[ks] = *(const bf16x8*)(qp + (size_t)(qrowA + 64) * HD_ + ks * 32 + lg * 8);
  }

  float mA[4], lA[4], mB[4], lB[4];
  f32x4 oA[8], oB[8];
#pragma unroll
  for (int j = 0; j < 4; ++j) { mA[j] = -INFINITY; lA[j] = 0.f; mB[j] = -INFINITY; lB[j] = 0.f; }
#pragma unroll
  for (int c = 0; c < 8; ++c) { oA[c] = (f32x4)(0.f); oB[c] = (f32x4)(0.f); }

  // stage K[64][128] into buffer buf; source pre-swizzled so linear dest + XOR'd reads match.
  auto stageK = [&](int buf, int k0) {
#pragma unroll
    for (int i = 0; i < 4; ++i) {
      const int slot = i * 256 + tid;
      const int row = slot >> 4, j16 = slot & 15;
      load_lds16(kp + (size_t)(k0 + row) * HD_ + ((j16 ^ (row & 7)) * 8),
                 (char*)&Ks[buf][0] + i * 4096 + w * 1024);
    }
  };

  // softmax for one row group: mask, row-reduce, defer-max rescale, exp, Ps write, pa read.
  auto softmax_g = [&](f32x4 (&sacc)[4], float (&m_run)[4], float (&l_run)[4],
                       f32x4 (&oacc)[8], const int rbase, const int k0,
                       const int (&mk4)[4], const int g, bf16x8 (&pa)[2]) {
    float mblk[4] = {-INFINITY, -INFINITY, -INFINITY, -INFINITY};
#pragma unroll
    for (int n = 0; n < 4; ++n) {
      const int kcol = k0 + n * 16 + lr;
#pragma unroll
      for (int j = 0; j < 4; ++j) {
        const int r = rbase + lg * 4 + j;
        float sv = sacc[n][j];
        const bool allowed = (kcol <= r) && (mk4[n] != 0 || kcol == r);
        sv = allowed ? sv : -1e9f;
        sacc[n][j] = sv;
        mblk[j] = fmaxf(mblk[j], sv);
      }
    }
#pragma unroll
    for (int xm = 1; xm < 16; xm <<= 1)
#pragma unroll
      for (int j = 0; j < 4; ++j)
        mblk[j] = fmaxf(mblk[j], __shfl_xor(mblk[j], xm, 64));

    // defer-max (T13)
    bool grow = false;
#pragma unroll
    for (int j = 0; j < 4; ++j) grow = grow || (mblk[j] > m_run[j] + 8.f);
    if (__any(grow)) {
      float alpha[4];
#pragma unroll
      for (int j = 0; j < 4; ++j) {
        const float mn = fmaxf(m_run[j], mblk[j]);
        alpha[j] = __expf(m_run[j] - mn);
        m_run[j] = mn;
        l_run[j] *= alpha[j];
      }
#pragma unroll
      for (int c = 0; c < 8; ++c)
#pragma unroll
        for (int j = 0; j < 4; ++j) oacc[c][j] *= alpha[j];
    }

    float psum[4] = {0.f, 0.f, 0.f, 0.f};
#pragma unroll
    for (int n = 0; n < 4; ++n)
#pragma unroll
      for (int j = 0; j < 4; ++j) {
        const float p = __expf(sacc[n][j] - m_run[j]);
        psum[j] += p;
        sacc[n][j] = p;
      }
#pragma unroll
    for (int xm = 1; xm < 16; xm <<= 1)
#pragma unroll
      for (int j = 0; j < 4; ++j)
        psum[j] += __shfl_xor(psum[j], xm, 64);
#pragma unroll
    for (int j = 0; j < 4; ++j) l_run[j] += psum[j];

    // P -> this group's private Ps slot; then read PV A-fragments (same-wave DS in-order)
#pragma unroll
    for (int n = 0; n < 4; ++n)
#pragma unroll
      for (int j = 0; j < 4; ++j)
        Ps[w][g][lg * 4 + j][n * 16 + lr] = __float2bfloat16(sacc[n][j]);
#pragma unroll
    for (int ks = 0; ks < 2; ++ks)
      pa[ks] = *(const bf16x8*)(&Ps[w][g][lr][ks * 32 + lg * 8]);
  };

  const int nt = 2 * qt + 2;
  stageK(0, 0);
  asm volatile("s_waitcnt vmcnt(0)" ::: "memory");
  __syncthreads();

  int cur = 0;
  for (int it = 0; it < nt; ++it) {
    const int k0 = it * 64;
    const bool doA = (it + 1 < nt);             // last tile is all-masked for group A
    if (it + 1 < nt) stageK(cur ^ 1, k0 + 64);  // prefetch next K tile (stays in flight)

    int mk4[4];
#pragma unroll
    for (int n = 0; n < 4; ++n) mk4[n] = mask[b * S_ + k0 + n * 16 + lr];

    const bf16* ksb = &Ks[cur][0];

    // QK^T for both groups, sharing each K-fragment read
    f32x4 sA[4] = {}, sB[4] = {};
    __builtin_amdgcn_s_setprio(1);
#pragma unroll
    for (int n = 0; n < 4; ++n) {
      const int krow = n * 16 + lr;
#pragma unroll
      for (int ks = 0; ks < 4; ++ks) {
        const int j16 = (ks * 4 + lg) ^ (krow & 7);
        const bf16x8 kf = *(const bf16x8*)(ksb + krow * 128 + j16 * 8);
        if (doA) sA[n] = __builtin_amdgcn_mfma_f32_16x16x32_bf16(qfA[ks], kf, sA[n], 0, 0, 0);
        sB[n] = __builtin_amdgcn_mfma_f32_16x16x32_bf16(qfB[ks], kf, sB[n], 0, 0, 0);
      }
    }
    __builtin_amdgcn_s_setprio(0);

    // independent A/B softmax (separate Ps slots -> interleavable chains)
    bf16x8 paA[2], paB[2];
    if (doA) softmax_g(sA, mA, lA, oA, q0 + w * 16, k0, mk4, 0, paA);
    softmax_g(sB, mB, lB, oB, q0 + 64 + w * 16, k0, mk4, 1, paB);

    // joint PV: each V fragment read once from global (vt is L2/L3-resident), used by both groups
    __builtin_amdgcn_s_setprio(1);
#pragma unroll
    for (int c = 0; c < 8; ++c) {
#pragma unroll
      for (int ks = 0; ks < 2; ++ks) {
        const bf16x8 vf = *(const bf16x8*)(vp + (size_t)(c * 16 + lr) * S_ + k0 + ks * 32 + lg * 8);
        if (doA) oA[c] = __builtin_amdgcn_mfma_f32_16x16x32_bf16(paA[ks], vf, oA[c], 0, 0, 0);
        oB[c] = __builtin_amdgcn_mfma_f32_16x16x32_bf16(paB[ks], vf, oB[c], 0, 0, 0);
      }
    }
    __builtin_amdgcn_s_setprio(0);

    asm volatile("s_waitcnt vmcnt(0)" ::: "memory");  // next K tile staged
    __syncthreads();                                   // all waves done with cur
    cur ^= 1;
  }

  // epilogue: normalize and write attn_b [B,S,H*hd] bf16
#pragma unroll
  for (int j = 0; j < 4; ++j) {
    const float invA = 1.f / lA[j];
    const float invB = 1.f / lB[j];
    const int rA = q0 + w * 16 + lg * 4 + j;
#pragma unroll
    for (int c = 0; c < 8; ++c) {
      attn_b[(size_t)(b * S_ + rA) * D_ + h * HD_ + c * 16 + lr] =
          __float2bfloat16(oA[c][j] * invA);
      attn_b[(size_t)(b * S_ + rA + 64) * D_ + h * HD_ + c * 16 + lr] =
          __float2bfloat16(oB[c][j] * invB);
    }
  }
}

extern "C" void kernel_launch(void* const* d_in, const int* in_sizes, int n_in,
                              void* d_out, int out_size, void* d_ws, size_t ws_size,
                              hipStream_t stream) {
  (void)in_sizes; (void)n_in; (void)out_size; (void)ws_size;
  const float* x        = (const float*)d_in[0];
  const int*   attn_mask= (const int*)d_in[1];
  const float* in_proj  = (const float*)d_in[2];
  const float* out_proj = (const float*)d_in[3];
  float* out = (float*)d_out;
  char* ws = (char*)d_ws;

  bf16*  xb    = (bf16*)(ws + 0);            // 16 MB (also attn_b later)
  bf16*  wqkvT = (bf16*)(ws + 16777216);     // 24 MB  ([3][2048][2048] = [6144][2048])
  bf16*  woT   = (bf16*)(ws + 41943040);     //  8 MB
  float* cost  = (float*)(ws + 50331648);
  float* sint  = (float*)(ws + 50855936);
  bf16*  vt    = (bf16*)(ws + 51380224);     // 16 MB
  bf16* qb = (bf16*)d_out;                   // d_out as scratch (dead before final GEMM)
  bf16* kb = (bf16*)((char*)d_out + 16777216);
  bf16* attn_b = xb;

  // allow 72 KB dynamic LDS (host-side, graph-capture safe)
  static int lds_ok = 0;
  if (!lds_ok) {
    (void)hipFuncSetAttribute((const void*)k_gemm_p<0>,
                              hipFuncAttributeMaxDynamicSharedMemorySize, 73728);
    (void)hipFuncSetAttribute((const void*)k_gemm_p<1>,
                              hipFuncAttributeMaxDynamicSharedMemorySize, 73728);
    lds_ok = 1;
  }

  k_convert<<<4096, 256, 0, stream>>>(x, xb);
  k_transpose<<<dim3(32, 32, 3), 256, 0, stream>>>(in_proj, wqkvT);
  k_transpose<<<dim3(32, 32, 1), 256, 0, stream>>>(out_proj, woT);
  k_rope_tables<<<512, 256, 0, stream>>>(cost, sint);
  k_gemm_p<0><<<dim3(32, 24), 512, 73728, stream>>>(xb, wqkvT, nullptr, qb, kb, vt, cost, sint);
  k_attn<<<dim3(16, 32), 256, 0, stream>>>(qb, kb, vt, attn_mask, attn_b);
  k_gemm_p<1><<<dim3(32, 8), 512, 73728, stream>>>(attn_b, woT, out, nullptr, nullptr, nullptr,
                                                   nullptr, nullptr);
}

// Round 11
// 314.661 us; speedup vs baseline: 1.2868x; 1.2868x over previous
//
#include <hip/hip_runtime.h>
#include <hip/hip_bf16.h>

#define B_   2
#define S_   2048
#define H_   16
#define HD_  128
#define D_   2048
#define BS_  4096
#define SCALE_ 0.08838834764831845f   // 1/sqrt(128), applied in QKV epilogue (t==0)

typedef __hip_bfloat16 bf16;
typedef float f32x4 __attribute__((ext_vector_type(4)));
typedef __bf16 bf16x8 __attribute__((ext_vector_type(8)));
typedef unsigned short u16x8 __attribute__((ext_vector_type(8)));
typedef unsigned short u16x4 __attribute__((ext_vector_type(4)));

static __device__ __forceinline__ unsigned short f2bf_u(float f) {
  bf16 h = __float2bfloat16(f);
  return __builtin_bit_cast(unsigned short, h);
}
static __device__ __forceinline__ void load_lds16(const void* g, void* l) {
  __builtin_amdgcn_global_load_lds((const __attribute__((address_space(1))) void*)g,
                                   (__attribute__((address_space(3))) void*)l, 16, 0, 0);
}

// ---------------- fp32 -> bf16 convert, 8 elems/thread ----------------
__global__ __launch_bounds__(256) void k_convert(const float* __restrict__ src,
                                                 bf16* __restrict__ dst) {
  const size_t i = ((size_t)blockIdx.x * 256 + threadIdx.x) * 8;
  const float4 a = *(const float4*)(src + i);
  const float4 b = *(const float4*)(src + i + 4);
  u16x8 o;
  o[0] = f2bf_u(a.x); o[1] = f2bf_u(a.y); o[2] = f2bf_u(a.z); o[3] = f2bf_u(a.w);
  o[4] = f2bf_u(b.x); o[5] = f2bf_u(b.y); o[6] = f2bf_u(b.z); o[7] = f2bf_u(b.w);
  *(u16x8*)(dst + i) = o;
}

// ---------- tiled transpose [2048][2048] fp32 -> bf16, one z-slice each ----------
__global__ __launch_bounds__(256) void k_transpose(const float* __restrict__ src0,
                                                   bf16* __restrict__ dst0) {
  const int z = blockIdx.z;
  const float* src = src0 + (size_t)z * D_ * D_;
  bf16* dst = dst0 + (size_t)z * D_ * D_;
  __shared__ float tile[64][65];
  const int t = threadIdx.x;
  const int x0 = blockIdx.x * 64, y0 = blockIdx.y * 64;
#pragma unroll
  for (int i = 0; i < 16; ++i) {
    int idx = t + i * 256, r = idx >> 6, c = idx & 63;
    tile[r][c] = src[(size_t)(y0 + r) * D_ + x0 + c];
  }
  __syncthreads();
#pragma unroll
  for (int i = 0; i < 16; ++i) {
    int idx = t + i * 256, c = idx >> 6, r = idx & 63;
    dst[(size_t)(x0 + c) * D_ + y0 + r] = __float2bfloat16(tile[r][c]);
  }
}

// ---------------- RoPE cos/sin tables [S][64] ----------------
__global__ __launch_bounds__(256) void k_rope_tables(float* __restrict__ cost,
                                                     float* __restrict__ sint) {
  const int idx = blockIdx.x * 256 + threadIdx.x;   // S_*64 total
  const int s = idx >> 6, d = idx & 63;
  const float inv = expf(-(float)d * (9.210340371976184f / 64.f)); // 10000^(-d/64)
  const float ang = (float)s * inv;
  cost[idx] = cosf(ang);
  sint[idx] = sinf(ang);
}

// ============ 128x256 GEMM, BK=32, 3-deep pipeline, counted vmcnt, 2 blocks/CU ============
// (unchanged from round 9 — see comments there)
template <int MODE>
__global__ __launch_bounds__(512, 4) void k_gemm_p(const bf16* __restrict__ A,
                                                   const bf16* __restrict__ Bt,
                                                   float* __restrict__ Cf,
                                                   bf16* __restrict__ qb,
                                                   bf16* __restrict__ kb,
                                                   bf16* __restrict__ vt,
                                                   const float* __restrict__ cost,
                                                   const float* __restrict__ sint) {
  extern __shared__ __align__(16) char smem[];   // 73728 bytes
  const int tid = threadIdx.x;
  const int w = tid >> 6, lane = tid & 63;
  const int wm = w >> 2, wn = w & 3;
  const int lr = lane & 15, lg = lane >> 4;
  const int brow = blockIdx.x * 128, bcol = blockIdx.y * 256;

  f32x4 acc[4][4] = {};

  auto stage = [&](int kt, int buf) {
    char* base = smem + buf * 24576;
    {  // A tile 128x32 (8KB): 1 load/thread
      const int row = tid >> 2, su = tid & 3;
      const int up = su ^ ((row >> 1) & 3);
      load_lds16(A + (size_t)(brow + row) * D_ + kt * 32 + up * 8, base + w * 1024);
    }
#pragma unroll
    for (int i = 0; i < 2; ++i) {  // B tile 256x32 (16KB): 2 loads/thread
      const int slot = i * 512 + tid;
      const int row = slot >> 2, su = slot & 3;
      const int up = su ^ ((row >> 1) & 3);
      load_lds16(Bt + (size_t)(bcol + row) * D_ + kt * 32 + up * 8,
                 base + 8192 + i * 8192 + w * 1024);
    }
  };

  const int NKT = D_ / 32;                       // 64
  stage(0, 0); stage(1, 1);                      // 6 loads/thread in flight
  int bs = 0;                                    // kt % 3
  for (int kt = 0; kt < NKT; ++kt) {
    if (kt < NKT - 1) asm volatile("s_waitcnt vmcnt(3)" ::: "memory");
    else              asm volatile("s_waitcnt vmcnt(0)" ::: "memory");
    __builtin_amdgcn_s_barrier();                // raw: prefetch loads stay in flight
    __builtin_amdgcn_sched_barrier(0);
    if (kt + 2 < NKT) {
      int sb = bs + 2; if (sb >= 3) sb -= 3;
      stage(kt + 2, sb);
    }

    const char* base = smem + bs * 24576;
    bf16x8 af[4], bf4[4];
#pragma unroll
    for (int q = 0; q < 4; ++q) {
      const int r = wm * 64 + q * 16 + lr;
      af[q] = *(const bf16x8*)(base + r * 64 + ((lg ^ ((r >> 1) & 3)) * 16));
    }
#pragma unroll
    for (int nf = 0; nf < 4; ++nf) {
      const int r = wn * 64 + nf * 16 + lr;
      bf4[nf] = *(const bf16x8*)(base + 8192 + r * 64 + ((lg ^ ((r >> 1) & 3)) * 16));
    }
    __builtin_amdgcn_s_setprio(1);
#pragma unroll
    for (int q = 0; q < 4; ++q)
#pragma unroll
      for (int nf = 0; nf < 4; ++nf)
        acc[q][nf] = __builtin_amdgcn_mfma_f32_16x16x32_bf16(af[q], bf4[nf], acc[q][nf], 0, 0, 0);
    __builtin_amdgcn_s_setprio(0);
    bs = (bs == 2) ? 0 : bs + 1;
  }

  if (MODE == 1) {
#pragma unroll
    for (int mf = 0; mf < 4; ++mf)
#pragma unroll
      for (int nf = 0; nf < 4; ++nf) {
        const int col = bcol + wn * 64 + nf * 16 + lr;
#pragma unroll
        for (int j = 0; j < 4; ++j) {
          const int row = brow + wm * 64 + mf * 16 + lg * 4 + j;
          Cf[(size_t)row * D_ + col] = acc[mf][nf][j];
        }
      }
  } else {
    const int t = bcol >> 11;                     // block-uniform (256 | 2048)
#pragma unroll
    for (int mf = 0; mf < 4; ++mf)
#pragma unroll
      for (int nf = 0; nf < 4; ++nf) {
        const int col = bcol + wn * 64 + nf * 16 + lr;
        const int h = (col >> 7) & (H_ - 1), mm = col & (HD_ - 1);
        if (t == 2) {
          const int row0 = brow + wm * 64 + mf * 16 + lg * 4;
          const int b = row0 >> 11, s0 = row0 & (S_ - 1);
          u16x4 pk;
#pragma unroll
          for (int j = 0; j < 4; ++j) pk[j] = f2bf_u(acc[mf][nf][j]);
          *(u16x4*)(vt + ((size_t)(b * H_ + h) * HD_ + mm) * S_ + s0) = pk;
        } else {
          const int i2 = mm >> 1;
          const bool odd = mm & 1;
#pragma unroll
          for (int j = 0; j < 4; ++j) {
            const int row = brow + wm * 64 + mf * 16 + lg * 4 + j;
            const int b = row >> 11, s = row & (S_ - 1);
            const float val = acc[mf][nf][j];
            const float part = __shfl_xor(val, 1, 64);   // col parity == lane parity
            const float c = cost[s * 64 + i2];
            const float sn = sint[s * 64 + i2];
            float o = odd ? (part * sn + val * c) : (val * c - part * sn);
            if (t == 0) o *= SCALE_;
            const int om = odd ? (64 + i2) : i2;
            bf16* dst = (t == 1) ? kb : qb;
            dst[((size_t)(b * H_ + h) * S_ + s) * HD_ + om] = __float2bfloat16(o);
          }
        }
      }
  }
}

// ---------------- flash attention: QBLK=128, K+V LDS dbuf (round-9 base) + joint PV + tail skip ----------------
// grid (16, B*H), complementary qt remap (round-5 load balance).
// Round-11 deltas vs round-9 (both exact, V stays LDS-staged):
//  (1) joint PV: softmax-A -> paA regs, softmax-B -> paB regs (Ps slot reused sequentially;
//      same-wave LDS ordering makes this safe), then ONE PV loop reading each V fragment once
//      and feeding both groups' MFMAs (16 ds_read_b128/iter instead of 32).
//  (2) last KV tile is fully masked for group A (kcol > r, diag out of range, m_run finite via
//      defer-max) -> skip A's QK^T/softmax/PV there.
__global__ __launch_bounds__(256, 2) void k_attn(const bf16* __restrict__ qb,
                                                 const bf16* __restrict__ kb,
                                                 const bf16* __restrict__ vt,
                                                 const int* __restrict__ mask,
                                                 bf16* __restrict__ attn_b) {
  const int tid = threadIdx.x, w = tid >> 6, lane = tid & 63;
  const int lr = lane & 15, lg = lane >> 4;
  const int qt = (blockIdx.y < 16) ? ((int)gridDim.x - 1 - (int)blockIdx.x)
                                   : (int)blockIdx.x;   // complementary pairing
  const int q0 = qt * 128;
  const int bh = blockIdx.y;
  const int b = bh >> 4, h = bh & (H_ - 1);
  const bf16* qp = qb + (size_t)bh * S_ * HD_;
  const bf16* kp = kb + (size_t)bh * S_ * HD_;
  const bf16* vp = vt + (size_t)bh * HD_ * S_;
  __shared__ __align__(16) bf16 Ks[2][64 * 128];   // 2 x 16 KB, XOR-swizzled rows
  __shared__ __align__(16) bf16 Vs[2][128 * 64];   // 2 x 16 KB, XOR-swizzled rows
  __shared__ __align__(16) bf16 Ps[4][16][80];     // per-wave P tile, reused A then B

  // Q fragments for both row groups (q pre-scaled by 1/sqrt(d) in GEMM epilogue)
  const int qrowA = q0 + w * 16 + lr;
  bf16x8 qfA[4], qfB[4];
#pragma unroll
  for (int ks = 0; ks < 4; ++ks) {
    qfA[ks] = *(const bf16x8*)(qp + (size_t)qrowA * HD_ + ks * 32 + lg * 8);
    qfB[ks] = *(const bf16x8*)(qp + (size_t)(qrowA + 64) * HD_ + ks * 32 + lg * 8);
  }

  float mA[4], lA[4], mB[4], lB[4];
  f32x4 oA[8], oB[8];
#pragma unroll
  for (int j = 0; j < 4; ++j) { mA[j] = -INFINITY; lA[j] = 0.f; mB[j] = -INFINITY; lB[j] = 0.f; }
#pragma unroll
  for (int c = 0; c < 8; ++c) { oA[c] = (f32x4)(0.f); oB[c] = (f32x4)(0.f); }

  // stage K[64][128] and V[128][64] into buffer buf; sources pre-swizzled so
  // linear LDS dest + XOR'd reads match.
  auto stage = [&](int buf, int k0) {
#pragma unroll
    for (int i = 0; i < 4; ++i) {
      const int slot = i * 256 + tid;
      const int row = slot >> 4, j16 = slot & 15;
      load_lds16(kp + (size_t)(k0 + row) * HD_ + ((j16 ^ (row & 7)) * 8),
                 (char*)&Ks[buf][0] + i * 4096 + w * 1024);
    }
#pragma unroll
    for (int i = 0; i < 4; ++i) {
      const int slot = i * 256 + tid;
      const int row = slot >> 3, j8 = slot & 7;
      load_lds16(vp + (size_t)row * S_ + k0 + ((j8 ^ (row & 7)) * 8),
                 (char*)&Vs[buf][0] + i * 4096 + w * 1024);
    }
  };

  // softmax for one row group; leaves P fragments in pa regs (Ps slot safe to reuse after).
  auto softmax_g = [&](f32x4 (&sacc)[4], float (&m_run)[4], float (&l_run)[4],
                       f32x4 (&oacc)[8], const int rbase, const int k0,
                       const int (&mk4)[4], bf16x8 (&pa)[2]) {
    float mblk[4] = {-INFINITY, -INFINITY, -INFINITY, -INFINITY};
#pragma unroll
    for (int n = 0; n < 4; ++n) {
      const int kcol = k0 + n * 16 + lr;
#pragma unroll
      for (int j = 0; j < 4; ++j) {
        const int r = rbase + lg * 4 + j;
        float sv = sacc[n][j];
        const bool allowed = (kcol <= r) && (mk4[n] != 0 || kcol == r);
        sv = allowed ? sv : -1e9f;
        sacc[n][j] = sv;
        mblk[j] = fmaxf(mblk[j], sv);
      }
    }
#pragma unroll
    for (int xm = 1; xm < 16; xm <<= 1)
#pragma unroll
      for (int j = 0; j < 4; ++j)
        mblk[j] = fmaxf(mblk[j], __shfl_xor(mblk[j], xm, 64));

    // defer-max (T13)
    bool grow = false;
#pragma unroll
    for (int j = 0; j < 4; ++j) grow = grow || (mblk[j] > m_run[j] + 8.f);
    if (__any(grow)) {
      float alpha[4];
#pragma unroll
      for (int j = 0; j < 4; ++j) {
        const float mn = fmaxf(m_run[j], mblk[j]);
        alpha[j] = __expf(m_run[j] - mn);
        m_run[j] = mn;
        l_run[j] *= alpha[j];
      }
#pragma unroll
      for (int c = 0; c < 8; ++c)
#pragma unroll
        for (int j = 0; j < 4; ++j) oacc[c][j] *= alpha[j];
    }

    float psum[4] = {0.f, 0.f, 0.f, 0.f};
#pragma unroll
    for (int n = 0; n < 4; ++n)
#pragma unroll
      for (int j = 0; j < 4; ++j) {
        const float p = __expf(sacc[n][j] - m_run[j]);
        psum[j] += p;
        sacc[n][j] = p;
      }
#pragma unroll
    for (int xm = 1; xm < 16; xm <<= 1)
#pragma unroll
      for (int j = 0; j < 4; ++j)
        psum[j] += __shfl_xor(psum[j], xm, 64);
#pragma unroll
    for (int j = 0; j < 4; ++j) l_run[j] += psum[j];

    // P -> per-wave LDS tile, then read PV A-fragments (same-wave DS ops are in-order)
#pragma unroll
    for (int n = 0; n < 4; ++n)
#pragma unroll
      for (int j = 0; j < 4; ++j)
        Ps[w][lg * 4 + j][n * 16 + lr] = __float2bfloat16(sacc[n][j]);
#pragma unroll
    for (int ks = 0; ks < 2; ++ks)
      pa[ks] = *(const bf16x8*)(&Ps[w][lr][ks * 32 + lg * 8]);
  };

  const int nt = 2 * qt + 2;
  stage(0, 0);
  asm volatile("s_waitcnt vmcnt(0)" ::: "memory");
  __syncthreads();

  int cur = 0;
  for (int it = 0; it < nt; ++it) {
    const int k0 = it * 64;
    const bool doA = (it + 1 < nt);             // last tile fully masked for group A
    if (it + 1 < nt) stage(cur ^ 1, k0 + 64);   // prefetch next tile (in flight across compute)

    int mk4[4];
#pragma unroll
    for (int n = 0; n < 4; ++n) mk4[n] = mask[b * S_ + k0 + n * 16 + lr];

    const bf16* ksb = &Ks[cur][0];
    const bf16* vsb = &Vs[cur][0];

    // QK^T for both groups, sharing each K-fragment read
    f32x4 sA[4] = {}, sB[4] = {};
    __builtin_amdgcn_s_setprio(1);
#pragma unroll
    for (int n = 0; n < 4; ++n) {
      const int krow = n * 16 + lr;
#pragma unroll
      for (int ks = 0; ks < 4; ++ks) {
        const int j16 = (ks * 4 + lg) ^ (krow & 7);
        const bf16x8 kf = *(const bf16x8*)(ksb + krow * 128 + j16 * 8);
        if (doA) sA[n] = __builtin_amdgcn_mfma_f32_16x16x32_bf16(qfA[ks], kf, sA[n], 0, 0, 0);
        sB[n] = __builtin_amdgcn_mfma_f32_16x16x32_bf16(qfB[ks], kf, sB[n], 0, 0, 0);
      }
    }
    __builtin_amdgcn_s_setprio(0);

    // sequential A/B softmax; pa regs survive the Ps slot reuse
    bf16x8 paA[2], paB[2];
    if (doA) softmax_g(sA, mA, lA, oA, q0 + w * 16, k0, mk4, paA);
    softmax_g(sB, mB, lB, oB, q0 + 64 + w * 16, k0, mk4, paB);

    // joint PV from LDS: each V fragment read once, feeds both groups
    __builtin_amdgcn_s_setprio(1);
#pragma unroll
    for (int c = 0; c < 8; ++c) {
#pragma unroll
      for (int ks = 0; ks < 2; ++ks) {
        const int vrow = c * 16 + lr;
        const int unit = (ks * 4 + lg) ^ (vrow & 7);
        const bf16x8 vf = *(const bf16x8*)(vsb + vrow * 64 + unit * 8);
        if (doA) oA[c] = __builtin_amdgcn_mfma_f32_16x16x32_bf16(paA[ks], vf, oA[c], 0, 0, 0);
        oB[c] = __builtin_amdgcn_mfma_f32_16x16x32_bf16(paB[ks], vf, oB[c], 0, 0, 0);
      }
    }
    __builtin_amdgcn_s_setprio(0);

    asm volatile("s_waitcnt vmcnt(0)" ::: "memory");  // next tile staged
    __syncthreads();                                   // all waves done with cur
    cur ^= 1;
  }

  // epilogue: normalize and write attn_b [B,S,H*hd] bf16
#pragma unroll
  for (int j = 0; j < 4; ++j) {
    const float invA = 1.f / lA[j];
    const float invB = 1.f / lB[j];
    const int rA = q0 + w * 16 + lg * 4 + j;
#pragma unroll
    for (int c = 0; c < 8; ++c) {
      attn_b[(size_t)(b * S_ + rA) * D_ + h * HD_ + c * 16 + lr] =
          __float2bfloat16(oA[c][j] * invA);
      attn_b[(size_t)(b * S_ + rA + 64) * D_ + h * HD_ + c * 16 + lr] =
          __float2bfloat16(oB[c][j] * invB);
    }
  }
}

extern "C" void kernel_launch(void* const* d_in, const int* in_sizes, int n_in,
                              void* d_out, int out_size, void* d_ws, size_t ws_size,
                              hipStream_t stream) {
  (void)in_sizes; (void)n_in; (void)out_size; (void)ws_size;
  const float* x        = (const float*)d_in[0];
  const int*   attn_mask= (const int*)d_in[1];
  const float* in_proj  = (const float*)d_in[2];
  const float* out_proj = (const float*)d_in[3];
  float* out = (float*)d_out;
  char* ws = (char*)d_ws;

  bf16*  xb    = (bf16*)(ws + 0);            // 16 MB (also attn_b later)
  bf16*  wqkvT = (bf16*)(ws + 16777216);     // 24 MB  ([3][2048][2048] = [6144][2048])
  bf16*  woT   = (bf16*)(ws + 41943040);     //  8 MB
  float* cost  = (float*)(ws + 50331648);
  float* sint  = (float*)(ws + 50855936);
  bf16*  vt    = (bf16*)(ws + 51380224);     // 16 MB
  bf16* qb = (bf16*)d_out;                   // d_out as scratch (dead before final GEMM)
  bf16* kb = (bf16*)((char*)d_out + 16777216);
  bf16* attn_b = xb;

  // allow 72 KB dynamic LDS (host-side, graph-capture safe)
  static int lds_ok = 0;
  if (!lds_ok) {
    (void)hipFuncSetAttribute((const void*)k_gemm_p<0>,
                              hipFuncAttributeMaxDynamicSharedMemorySize, 73728);
    (void)hipFuncSetAttribute((const void*)k_gemm_p<1>,
                              hipFuncAttributeMaxDynamicSharedMemorySize, 73728);
    lds_ok = 1;
  }

  k_convert<<<4096, 256, 0, stream>>>(x, xb);
  k_transpose<<<dim3(32, 32, 3), 256, 0, stream>>>(in_proj, wqkvT);
  k_transpose<<<dim3(32, 32, 1), 256, 0, stream>>>(out_proj, woT);
  k_rope_tables<<<512, 256, 0, stream>>>(cost, sint);
  k_gemm_p<0><<<dim3(32, 24), 512, 73728, stream>>>(xb, wqkvT, nullptr, qb, kb, vt, cost, sint);
  k_attn<<<dim3(16, 32), 256, 0, stream>>>(qb, kb, vt, attn_mask, attn_b);
  k_gemm_p<1><<<dim3(32, 8), 512, 73728, stream>>>(attn_b, woT, out, nullptr, nullptr, nullptr,
                                                   nullptr, nullptr);
}

// Round 12
// 306.014 us; speedup vs baseline: 1.3232x; 1.0283x over previous
//
#include <hip/hip_runtime.h>
#include <hip/hip_bf16.h>

#define B_   2
#define S_   2048
#define H_   16
#define HD_  128
#define D_   2048
#define BS_  4096
#define SCALE_ 0.08838834764831845f   // 1/sqrt(128), applied in QKV epilogue (t==0)

typedef __hip_bfloat16 bf16;
typedef float f32x4 __attribute__((ext_vector_type(4)));
typedef __bf16 bf16x8 __attribute__((ext_vector_type(8)));
typedef unsigned short u16x8 __attribute__((ext_vector_type(8)));
typedef unsigned short u16x4 __attribute__((ext_vector_type(4)));

static __device__ __forceinline__ unsigned short f2bf_u(float f) {
  bf16 h = __float2bfloat16(f);
  return __builtin_bit_cast(unsigned short, h);
}
static __device__ __forceinline__ void load_lds16(const void* g, void* l) {
  __builtin_amdgcn_global_load_lds((const __attribute__((address_space(1))) void*)g,
                                   (__attribute__((address_space(3))) void*)l, 16, 0, 0);
}

// ---------------- fp32 -> bf16 convert, 8 elems/thread ----------------
__global__ __launch_bounds__(256) void k_convert(const float* __restrict__ src,
                                                 bf16* __restrict__ dst) {
  const size_t i = ((size_t)blockIdx.x * 256 + threadIdx.x) * 8;
  const float4 a = *(const float4*)(src + i);
  const float4 b = *(const float4*)(src + i + 4);
  u16x8 o;
  o[0] = f2bf_u(a.x); o[1] = f2bf_u(a.y); o[2] = f2bf_u(a.z); o[3] = f2bf_u(a.w);
  o[4] = f2bf_u(b.x); o[5] = f2bf_u(b.y); o[6] = f2bf_u(b.z); o[7] = f2bf_u(b.w);
  *(u16x8*)(dst + i) = o;
}

// ---------- tiled transpose [2048][2048] fp32 -> bf16, one z-slice each ----------
__global__ __launch_bounds__(256) void k_transpose(const float* __restrict__ src0,
                                                   bf16* __restrict__ dst0) {
  const int z = blockIdx.z;
  const float* src = src0 + (size_t)z * D_ * D_;
  bf16* dst = dst0 + (size_t)z * D_ * D_;
  __shared__ float tile[64][65];
  const int t = threadIdx.x;
  const int x0 = blockIdx.x * 64, y0 = blockIdx.y * 64;
#pragma unroll
  for (int i = 0; i < 16; ++i) {
    int idx = t + i * 256, r = idx >> 6, c = idx & 63;
    tile[r][c] = src[(size_t)(y0 + r) * D_ + x0 + c];
  }
  __syncthreads();
#pragma unroll
  for (int i = 0; i < 16; ++i) {
    int idx = t + i * 256, c = idx >> 6, r = idx & 63;
    dst[(size_t)(x0 + c) * D_ + y0 + r] = __float2bfloat16(tile[r][c]);
  }
}

// ---------------- RoPE cos/sin tables [S][64] ----------------
__global__ __launch_bounds__(256) void k_rope_tables(float* __restrict__ cost,
                                                     float* __restrict__ sint) {
  const int idx = blockIdx.x * 256 + threadIdx.x;   // S_*64 total
  const int s = idx >> 6, d = idx & 63;
  const float inv = expf(-(float)d * (9.210340371976184f / 64.f)); // 10000^(-d/64)
  const float ang = (float)s * inv;
  cost[idx] = cosf(ang);
  sint[idx] = sinf(ang);
}

// ============ 128xBN GEMM, BK=32, 3-deep pipeline, counted vmcnt ============
// MODE 0: BN=256 (QKV, fused RoPE epilogue), grid (32,24)=768 = 3x256 even rounds.
// MODE 1: BN=128 (out-proj, fp32 C), grid (32,16)=512 = 2/CU even — fixes the
//         1-block/CU zero-co-residency of the (32,8) 256-wide version.
// Pipeline/swizzle identical to round 9 (see comments there); stage = 1 A-load +
// BN/128 B-loads per thread; counted wait = loads-per-stage.
template <int MODE>
__global__ __launch_bounds__(512, 4) void k_gemm_p(const bf16* __restrict__ A,
                                                   const bf16* __restrict__ Bt,
                                                   float* __restrict__ Cf,
                                                   bf16* __restrict__ qb,
                                                   bf16* __restrict__ kb,
                                                   bf16* __restrict__ vt,
                                                   const float* __restrict__ cost,
                                                   const float* __restrict__ sint) {
  constexpr int BN = (MODE == 1) ? 128 : 256;
  constexpr int NF = BN / 64;                    // col fragments per wave
  constexpr int BSTRIDE = 8192 + BN * 64;        // bytes per LDS buffer
  extern __shared__ __align__(16) char smem[];
  const int tid = threadIdx.x;
  const int w = tid >> 6, lane = tid & 63;
  const int wm = w >> 2, wn = w & 3;
  const int lr = lane & 15, lg = lane >> 4;
  const int brow = blockIdx.x * 128, bcol = blockIdx.y * BN;

  f32x4 acc[4][NF] = {};

  auto stage = [&](int kt, int buf) {
    char* base = smem + buf * BSTRIDE;
    {  // A tile 128x32 (8KB): 1 load/thread
      const int row = tid >> 2, su = tid & 3;
      const int up = su ^ ((row >> 1) & 3);
      load_lds16(A + (size_t)(brow + row) * D_ + kt * 32 + up * 8, base + w * 1024);
    }
#pragma unroll
    for (int i = 0; i < BN / 128; ++i) {  // B tile BNx32: BN/128 loads/thread
      const int slot = i * 512 + tid;
      const int row = slot >> 2, su = slot & 3;
      const int up = su ^ ((row >> 1) & 3);
      load_lds16(Bt + (size_t)(bcol + row) * D_ + kt * 32 + up * 8,
                 base + 8192 + i * 8192 + w * 1024);
    }
  };

  const int NKT = D_ / 32;                       // 64
  stage(0, 0); stage(1, 1);
  int bs = 0;                                    // kt % 3
  for (int kt = 0; kt < NKT; ++kt) {
    if (kt < NKT - 1) {
      if constexpr (MODE == 1) asm volatile("s_waitcnt vmcnt(2)" ::: "memory");
      else                     asm volatile("s_waitcnt vmcnt(3)" ::: "memory");
    } else {
      asm volatile("s_waitcnt vmcnt(0)" ::: "memory");
    }
    __builtin_amdgcn_s_barrier();                // raw: prefetch loads stay in flight
    __builtin_amdgcn_sched_barrier(0);
    if (kt + 2 < NKT) {
      int sb = bs + 2; if (sb >= 3) sb -= 3;
      stage(kt + 2, sb);
    }

    const char* base = smem + bs * BSTRIDE;
    bf16x8 af[4], bf4[NF];
#pragma unroll
    for (int q = 0; q < 4; ++q) {
      const int r = wm * 64 + q * 16 + lr;
      af[q] = *(const bf16x8*)(base + r * 64 + ((lg ^ ((r >> 1) & 3)) * 16));
    }
#pragma unroll
    for (int nf = 0; nf < NF; ++nf) {
      const int r = wn * (NF * 16) + nf * 16 + lr;
      bf4[nf] = *(const bf16x8*)(base + 8192 + r * 64 + ((lg ^ ((r >> 1) & 3)) * 16));
    }
    __builtin_amdgcn_s_setprio(1);
#pragma unroll
    for (int q = 0; q < 4; ++q)
#pragma unroll
      for (int nf = 0; nf < NF; ++nf)
        acc[q][nf] = __builtin_amdgcn_mfma_f32_16x16x32_bf16(af[q], bf4[nf], acc[q][nf], 0, 0, 0);
    __builtin_amdgcn_s_setprio(0);
    bs = (bs == 2) ? 0 : bs + 1;
  }

  if (MODE == 1) {
#pragma unroll
    for (int mf = 0; mf < 4; ++mf)
#pragma unroll
      for (int nf = 0; nf < NF; ++nf) {
        const int col = bcol + wn * (NF * 16) + nf * 16 + lr;
#pragma unroll
        for (int j = 0; j < 4; ++j) {
          const int row = brow + wm * 64 + mf * 16 + lg * 4 + j;
          Cf[(size_t)row * D_ + col] = acc[mf][nf][j];
        }
      }
  } else {
    const int t = bcol >> 11;                     // block-uniform (256 | 2048)
#pragma unroll
    for (int mf = 0; mf < 4; ++mf)
#pragma unroll
      for (int nf = 0; nf < NF; ++nf) {
        const int col = bcol + wn * (NF * 16) + nf * 16 + lr;
        const int h = (col >> 7) & (H_ - 1), mm = col & (HD_ - 1);
        if (t == 2) {
          const int row0 = brow + wm * 64 + mf * 16 + lg * 4;
          const int b = row0 >> 11, s0 = row0 & (S_ - 1);
          u16x4 pk;
#pragma unroll
          for (int j = 0; j < 4; ++j) pk[j] = f2bf_u(acc[mf][nf][j]);
          *(u16x4*)(vt + ((size_t)(b * H_ + h) * HD_ + mm) * S_ + s0) = pk;
        } else {
          const int i2 = mm >> 1;
          const bool odd = mm & 1;
#pragma unroll
          for (int j = 0; j < 4; ++j) {
            const int row = brow + wm * 64 + mf * 16 + lg * 4 + j;
            const int b = row >> 11, s = row & (S_ - 1);
            const float val = acc[mf][nf][j];
            const float part = __shfl_xor(val, 1, 64);   // col parity == lane parity
            const float c = cost[s * 64 + i2];
            const float sn = sint[s * 64 + i2];
            float o = odd ? (part * sn + val * c) : (val * c - part * sn);
            if (t == 0) o *= SCALE_;
            const int om = odd ? (64 + i2) : i2;
            bf16* dst = (t == 1) ? kb : qb;
            dst[((size_t)(b * H_ + h) * S_ + s) * HD_ + om] = __float2bfloat16(o);
          }
        }
      }
  }
}

// ---------------- flash attention: QBLK=128, K+V dbuf via global_load_lds (round-9 exact) ----------------
// grid (16, B*H). Complementary qt remap for CU load balance. Per-group sm_pv ordering
// (softmax-A -> PV-A -> softmax-B -> PV-B) keeps PV-A's MFMA burst overlapping softmax-B's
// VALU chain (round-11's joint PV lost this overlap and regressed — do not re-merge).
__global__ __launch_bounds__(256, 2) void k_attn(const bf16* __restrict__ qb,
                                                 const bf16* __restrict__ kb,
                                                 const bf16* __restrict__ vt,
                                                 const int* __restrict__ mask,
                                                 bf16* __restrict__ attn_b) {
  const int tid = threadIdx.x, w = tid >> 6, lane = tid & 63;
  const int lr = lane & 15, lg = lane >> 4;
  const int qt = (blockIdx.y < 16) ? ((int)gridDim.x - 1 - (int)blockIdx.x)
                                   : (int)blockIdx.x;   // complementary pairing
  const int q0 = qt * 128;
  const int bh = blockIdx.y;
  const int b = bh >> 4, h = bh & (H_ - 1);
  const bf16* qp = qb + (size_t)bh * S_ * HD_;
  const bf16* kp = kb + (size_t)bh * S_ * HD_;
  const bf16* vp = vt + (size_t)bh * HD_ * S_;
  __shared__ __align__(16) bf16 Ks[2][64 * 128];   // 2 x 16 KB, XOR-swizzled rows
  __shared__ __align__(16) bf16 Vs[2][128 * 64];   // 2 x 16 KB, XOR-swizzled rows
  __shared__ __align__(16) bf16 Ps[4][16][80];     // per-wave P tile, reused A then B

  const int qrowA = q0 + w * 16 + lr;
  bf16x8 qfA[4], qfB[4];
#pragma unroll
  for (int ks = 0; ks < 4; ++ks) {
    qfA[ks] = *(const bf16x8*)(qp + (size_t)qrowA * HD_ + ks * 32 + lg * 8);
    qfB[ks] = *(const bf16x8*)(qp + (size_t)(qrowA + 64) * HD_ + ks * 32 + lg * 8);
  }

  float mA[4], lA[4], mB[4], lB[4];
  f32x4 oA[8], oB[8];
#pragma unroll
  for (int j = 0; j < 4; ++j) { mA[j] = -INFINITY; lA[j] = 0.f; mB[j] = -INFINITY; lB[j] = 0.f; }
#pragma unroll
  for (int c = 0; c < 8; ++c) { oA[c] = (f32x4)(0.f); oB[c] = (f32x4)(0.f); }

  auto stage = [&](int buf, int k0) {
#pragma unroll
    for (int i = 0; i < 4; ++i) {
      const int slot = i * 256 + tid;
      const int row = slot >> 4, j16 = slot & 15;
      load_lds16(kp + (size_t)(k0 + row) * HD_ + ((j16 ^ (row & 7)) * 8),
                 (char*)&Ks[buf][0] + i * 4096 + w * 1024);
    }
#pragma unroll
    for (int i = 0; i < 4; ++i) {
      const int slot = i * 256 + tid;
      const int row = slot >> 3, j8 = slot & 7;
      load_lds16(vp + (size_t)row * S_ + k0 + ((j8 ^ (row & 7)) * 8),
                 (char*)&Vs[buf][0] + i * 4096 + w * 1024);
    }
  };

  // softmax + PV for one row group (Ps slot reused sequentially; same-wave DS ops are in-order)
  auto sm_pv = [&](f32x4 (&sacc)[4], float (&m_run)[4], float (&l_run)[4],
                   f32x4 (&oacc)[8], const int rbase, const int k0,
                   const int (&mk4)[4], const bf16* vsb) {
    float mblk[4] = {-INFINITY, -INFINITY, -INFINITY, -INFINITY};
#pragma unroll
    for (int n = 0; n < 4; ++n) {
      const int kcol = k0 + n * 16 + lr;
#pragma unroll
      for (int j = 0; j < 4; ++j) {
        const int r = rbase + lg * 4 + j;
        float sv = sacc[n][j];
        const bool allowed = (kcol <= r) && (mk4[n] != 0 || kcol == r);
        sv = allowed ? sv : -1e9f;
        sacc[n][j] = sv;
        mblk[j] = fmaxf(mblk[j], sv);
      }
    }
#pragma unroll
    for (int xm = 1; xm < 16; xm <<= 1)
#pragma unroll
      for (int j = 0; j < 4; ++j)
        mblk[j] = fmaxf(mblk[j], __shfl_xor(mblk[j], xm, 64));

    // defer-max (T13)
    bool grow = false;
#pragma unroll
    for (int j = 0; j < 4; ++j) grow = grow || (mblk[j] > m_run[j] + 8.f);
    if (__any(grow)) {
      float alpha[4];
#pragma unroll
      for (int j = 0; j < 4; ++j) {
        const float mn = fmaxf(m_run[j], mblk[j]);
        alpha[j] = __expf(m_run[j] - mn);
        m_run[j] = mn;
        l_run[j] *= alpha[j];
      }
#pragma unroll
      for (int c = 0; c < 8; ++c)
#pragma unroll
        for (int j = 0; j < 4; ++j) oacc[c][j] *= alpha[j];
    }

    float psum[4] = {0.f, 0.f, 0.f, 0.f};
#pragma unroll
    for (int n = 0; n < 4; ++n)
#pragma unroll
      for (int j = 0; j < 4; ++j) {
        const float p = __expf(sacc[n][j] - m_run[j]);
        psum[j] += p;
        sacc[n][j] = p;
      }
#pragma unroll
    for (int xm = 1; xm < 16; xm <<= 1)
#pragma unroll
      for (int j = 0; j < 4; ++j)
        psum[j] += __shfl_xor(psum[j], xm, 64);
#pragma unroll
    for (int j = 0; j < 4; ++j) l_run[j] += psum[j];

    // P -> per-wave LDS tile
#pragma unroll
    for (int n = 0; n < 4; ++n)
#pragma unroll
      for (int j = 0; j < 4; ++j)
        Ps[w][lg * 4 + j][n * 16 + lr] = __float2bfloat16(sacc[n][j]);

    bf16x8 pa[2];
#pragma unroll
    for (int ks = 0; ks < 2; ++ks)
      pa[ks] = *(const bf16x8*)(&Ps[w][lr][ks * 32 + lg * 8]);
    __builtin_amdgcn_s_setprio(1);
#pragma unroll
    for (int c = 0; c < 8; ++c) {
#pragma unroll
      for (int ks = 0; ks < 2; ++ks) {
        const int vrow = c * 16 + lr;
        const int unit = (ks * 4 + lg) ^ (vrow & 7);
        const bf16x8 vf = *(const bf16x8*)(vsb + vrow * 64 + unit * 8);
        oacc[c] = __builtin_amdgcn_mfma_f32_16x16x32_bf16(pa[ks], vf, oacc[c], 0, 0, 0);
      }
    }
    __builtin_amdgcn_s_setprio(0);
  };

  const int nt = 2 * qt + 2;
  stage(0, 0);
  asm volatile("s_waitcnt vmcnt(0)" ::: "memory");
  __syncthreads();

  int cur = 0;
  for (int it = 0; it < nt; ++it) {
    const int k0 = it * 64;
    if (it + 1 < nt) stage(cur ^ 1, k0 + 64);   // prefetch next tile (in flight across compute)

    int mk4[4];
#pragma unroll
    for (int n = 0; n < 4; ++n) mk4[n] = mask[b * S_ + k0 + n * 16 + lr];

    const bf16* ksb = &Ks[cur][0];
    const bf16* vsb = &Vs[cur][0];

    // QK^T for both groups, sharing each K-fragment read
    f32x4 sA[4] = {}, sB[4] = {};
    __builtin_amdgcn_s_setprio(1);
#pragma unroll
    for (int n = 0; n < 4; ++n) {
      const int krow = n * 16 + lr;
#pragma unroll
      for (int ks = 0; ks < 4; ++ks) {
        const int j16 = (ks * 4 + lg) ^ (krow & 7);
        const bf16x8 kf = *(const bf16x8*)(ksb + krow * 128 + j16 * 8);
        sA[n] = __builtin_amdgcn_mfma_f32_16x16x32_bf16(qfA[ks], kf, sA[n], 0, 0, 0);
        sB[n] = __builtin_amdgcn_mfma_f32_16x16x32_bf16(qfB[ks], kf, sB[n], 0, 0, 0);
      }
    }
    __builtin_amdgcn_s_setprio(0);

    sm_pv(sA, mA, lA, oA, q0 + w * 16, k0, mk4, vsb);
    sm_pv(sB, mB, lB, oB, q0 + 64 + w * 16, k0, mk4, vsb);

    asm volatile("s_waitcnt vmcnt(0)" ::: "memory");  // next tile staged
    __syncthreads();                                   // all waves done with cur
    cur ^= 1;
  }

  // epilogue: normalize and write attn_b [B,S,H*hd] bf16
#pragma unroll
  for (int j = 0; j < 4; ++j) {
    const float invA = 1.f / lA[j];
    const float invB = 1.f / lB[j];
    const int rA = q0 + w * 16 + lg * 4 + j;
#pragma unroll
    for (int c = 0; c < 8; ++c) {
      attn_b[(size_t)(b * S_ + rA) * D_ + h * HD_ + c * 16 + lr] =
          __float2bfloat16(oA[c][j] * invA);
      attn_b[(size_t)(b * S_ + rA + 64) * D_ + h * HD_ + c * 16 + lr] =
          __float2bfloat16(oB[c][j] * invB);
    }
  }
}

extern "C" void kernel_launch(void* const* d_in, const int* in_sizes, int n_in,
                              void* d_out, int out_size, void* d_ws, size_t ws_size,
                              hipStream_t stream) {
  (void)in_sizes; (void)n_in; (void)out_size; (void)ws_size;
  const float* x        = (const float*)d_in[0];
  const int*   attn_mask= (const int*)d_in[1];
  const float* in_proj  = (const float*)d_in[2];
  const float* out_proj = (const float*)d_in[3];
  float* out = (float*)d_out;
  char* ws = (char*)d_ws;

  bf16*  xb    = (bf16*)(ws + 0);            // 16 MB (also attn_b later)
  bf16*  wqkvT = (bf16*)(ws + 16777216);     // 24 MB  ([3][2048][2048] = [6144][2048])
  bf16*  woT   = (bf16*)(ws + 41943040);     //  8 MB
  float* cost  = (float*)(ws + 50331648);
  float* sint  = (float*)(ws + 50855936);
  bf16*  vt    = (bf16*)(ws + 51380224);     // 16 MB
  bf16* qb = (bf16*)d_out;                   // d_out as scratch (dead before final GEMM)
  bf16* kb = (bf16*)((char*)d_out + 16777216);
  bf16* attn_b = xb;

  // allow dynamic LDS (host-side, graph-capture safe)
  static int lds_ok = 0;
  if (!lds_ok) {
    (void)hipFuncSetAttribute((const void*)k_gemm_p<0>,
                              hipFuncAttributeMaxDynamicSharedMemorySize, 73728);
    (void)hipFuncSetAttribute((const void*)k_gemm_p<1>,
                              hipFuncAttributeMaxDynamicSharedMemorySize, 49152);
    lds_ok = 1;
  }

  k_convert<<<4096, 256, 0, stream>>>(x, xb);
  k_transpose<<<dim3(32, 32, 3), 256, 0, stream>>>(in_proj, wqkvT);
  k_transpose<<<dim3(32, 32, 1), 256, 0, stream>>>(out_proj, woT);
  k_rope_tables<<<512, 256, 0, stream>>>(cost, sint);
  k_gemm_p<0><<<dim3(32, 24), 512, 73728, stream>>>(xb, wqkvT, nullptr, qb, kb, vt, cost, sint);
  k_attn<<<dim3(16, 32), 256, 0, stream>>>(qb, kb, vt, attn_mask, attn_b);
  k_gemm_p<1><<<dim3(32, 16), 512, 49152, stream>>>(attn_b, woT, out, nullptr, nullptr, nullptr,
                                                    nullptr, nullptr);
}

// Round 13
// 278.500 us; speedup vs baseline: 1.4539x; 1.0988x over previous
//
#include <hip/hip_runtime.h>
#include <hip/hip_bf16.h>

#define B_   2
#define S_   2048
#define H_   16
#define HD_  128
#define D_   2048
#define BS_  4096
#define SCALE_ 0.08838834764831845f   // 1/sqrt(128), applied in QKV epilogue (t==0)

typedef __hip_bfloat16 bf16;
typedef float f32x4 __attribute__((ext_vector_type(4)));
typedef __bf16 bf16x8 __attribute__((ext_vector_type(8)));
typedef unsigned short u16x8 __attribute__((ext_vector_type(8)));
typedef unsigned short u16x4 __attribute__((ext_vector_type(4)));

static __device__ __forceinline__ unsigned short f2bf_u(float f) {
  bf16 h = __float2bfloat16(f);
  return __builtin_bit_cast(unsigned short, h);
}
static __device__ __forceinline__ void load_lds16(const void* g, void* l) {
  __builtin_amdgcn_global_load_lds((const __attribute__((address_space(1))) void*)g,
                                   (__attribute__((address_space(3))) void*)l, 16, 0, 0);
}

// ---------------- fp32 -> bf16 convert, 8 elems/thread ----------------
__global__ __launch_bounds__(256) void k_convert(const float* __restrict__ src,
                                                 bf16* __restrict__ dst) {
  const size_t i = ((size_t)blockIdx.x * 256 + threadIdx.x) * 8;
  const float4 a = *(const float4*)(src + i);
  const float4 b = *(const float4*)(src + i + 4);
  u16x8 o;
  o[0] = f2bf_u(a.x); o[1] = f2bf_u(a.y); o[2] = f2bf_u(a.z); o[3] = f2bf_u(a.w);
  o[4] = f2bf_u(b.x); o[5] = f2bf_u(b.y); o[6] = f2bf_u(b.z); o[7] = f2bf_u(b.w);
  *(u16x8*)(dst + i) = o;
}

// ---------- tiled transpose [2048][2048] fp32 -> bf16, one z-slice each ----------
__global__ __launch_bounds__(256) void k_transpose(const float* __restrict__ src0,
                                                   bf16* __restrict__ dst0) {
  const int z = blockIdx.z;
  const float* src = src0 + (size_t)z * D_ * D_;
  bf16* dst = dst0 + (size_t)z * D_ * D_;
  __shared__ float tile[64][65];
  const int t = threadIdx.x;
  const int x0 = blockIdx.x * 64, y0 = blockIdx.y * 64;
#pragma unroll
  for (int i = 0; i < 16; ++i) {
    int idx = t + i * 256, r = idx >> 6, c = idx & 63;
    tile[r][c] = src[(size_t)(y0 + r) * D_ + x0 + c];
  }
  __syncthreads();
#pragma unroll
  for (int i = 0; i < 16; ++i) {
    int idx = t + i * 256, c = idx >> 6, r = idx & 63;
    dst[(size_t)(x0 + c) * D_ + y0 + r] = __float2bfloat16(tile[r][c]);
  }
}

// ---------------- RoPE cos/sin tables [S][64] ----------------
__global__ __launch_bounds__(256) void k_rope_tables(float* __restrict__ cost,
                                                     float* __restrict__ sint) {
  const int idx = blockIdx.x * 256 + threadIdx.x;   // S_*64 total
  const int s = idx >> 6, d = idx & 63;
  const float inv = expf(-(float)d * (9.210340371976184f / 64.f)); // 10000^(-d/64)
  const float ang = (float)s * inv;
  cost[idx] = cosf(ang);
  sint[idx] = sinf(ang);
}

// ============ 128xBN GEMM, BK=32, 3-deep pipeline, counted vmcnt (round-12, unchanged) ============
template <int MODE>
__global__ __launch_bounds__(512, 4) void k_gemm_p(const bf16* __restrict__ A,
                                                   const bf16* __restrict__ Bt,
                                                   float* __restrict__ Cf,
                                                   bf16* __restrict__ qb,
                                                   bf16* __restrict__ kb,
                                                   bf16* __restrict__ vt,
                                                   const float* __restrict__ cost,
                                                   const float* __restrict__ sint) {
  constexpr int BN = (MODE == 1) ? 128 : 256;
  constexpr int NF = BN / 64;                    // col fragments per wave
  constexpr int BSTRIDE = 8192 + BN * 64;        // bytes per LDS buffer
  extern __shared__ __align__(16) char smem[];
  const int tid = threadIdx.x;
  const int w = tid >> 6, lane = tid & 63;
  const int wm = w >> 2, wn = w & 3;
  const int lr = lane & 15, lg = lane >> 4;
  const int brow = blockIdx.x * 128, bcol = blockIdx.y * BN;

  f32x4 acc[4][NF] = {};

  auto stage = [&](int kt, int buf) {
    char* base = smem + buf * BSTRIDE;
    {  // A tile 128x32 (8KB): 1 load/thread
      const int row = tid >> 2, su = tid & 3;
      const int up = su ^ ((row >> 1) & 3);
      load_lds16(A + (size_t)(brow + row) * D_ + kt * 32 + up * 8, base + w * 1024);
    }
#pragma unroll
    for (int i = 0; i < BN / 128; ++i) {  // B tile BNx32: BN/128 loads/thread
      const int slot = i * 512 + tid;
      const int row = slot >> 2, su = slot & 3;
      const int up = su ^ ((row >> 1) & 3);
      load_lds16(Bt + (size_t)(bcol + row) * D_ + kt * 32 + up * 8,
                 base + 8192 + i * 8192 + w * 1024);
    }
  };

  const int NKT = D_ / 32;                       // 64
  stage(0, 0); stage(1, 1);
  int bs = 0;                                    // kt % 3
  for (int kt = 0; kt < NKT; ++kt) {
    if (kt < NKT - 1) {
      if constexpr (MODE == 1) asm volatile("s_waitcnt vmcnt(2)" ::: "memory");
      else                     asm volatile("s_waitcnt vmcnt(3)" ::: "memory");
    } else {
      asm volatile("s_waitcnt vmcnt(0)" ::: "memory");
    }
    __builtin_amdgcn_s_barrier();                // raw: prefetch loads stay in flight
    __builtin_amdgcn_sched_barrier(0);
    if (kt + 2 < NKT) {
      int sb = bs + 2; if (sb >= 3) sb -= 3;
      stage(kt + 2, sb);
    }

    const char* base = smem + bs * BSTRIDE;
    bf16x8 af[4], bf4[NF];
#pragma unroll
    for (int q = 0; q < 4; ++q) {
      const int r = wm * 64 + q * 16 + lr;
      af[q] = *(const bf16x8*)(base + r * 64 + ((lg ^ ((r >> 1) & 3)) * 16));
    }
#pragma unroll
    for (int nf = 0; nf < NF; ++nf) {
      const int r = wn * (NF * 16) + nf * 16 + lr;
      bf4[nf] = *(const bf16x8*)(base + 8192 + r * 64 + ((lg ^ ((r >> 1) & 3)) * 16));
    }
    __builtin_amdgcn_s_setprio(1);
#pragma unroll
    for (int q = 0; q < 4; ++q)
#pragma unroll
      for (int nf = 0; nf < NF; ++nf)
        acc[q][nf] = __builtin_amdgcn_mfma_f32_16x16x32_bf16(af[q], bf4[nf], acc[q][nf], 0, 0, 0);
    __builtin_amdgcn_s_setprio(0);
    bs = (bs == 2) ? 0 : bs + 1;
  }

  if (MODE == 1) {
#pragma unroll
    for (int mf = 0; mf < 4; ++mf)
#pragma unroll
      for (int nf = 0; nf < NF; ++nf) {
        const int col = bcol + wn * (NF * 16) + nf * 16 + lr;
#pragma unroll
        for (int j = 0; j < 4; ++j) {
          const int row = brow + wm * 64 + mf * 16 + lg * 4 + j;
          Cf[(size_t)row * D_ + col] = acc[mf][nf][j];
        }
      }
  } else {
    const int t = bcol >> 11;                     // block-uniform (256 | 2048)
#pragma unroll
    for (int mf = 0; mf < 4; ++mf)
#pragma unroll
      for (int nf = 0; nf < NF; ++nf) {
        const int col = bcol + wn * (NF * 16) + nf * 16 + lr;
        const int h = (col >> 7) & (H_ - 1), mm = col & (HD_ - 1);
        if (t == 2) {
          const int row0 = brow + wm * 64 + mf * 16 + lg * 4;
          const int b = row0 >> 11, s0 = row0 & (S_ - 1);
          u16x4 pk;
#pragma unroll
          for (int j = 0; j < 4; ++j) pk[j] = f2bf_u(acc[mf][nf][j]);
          *(u16x4*)(vt + ((size_t)(b * H_ + h) * HD_ + mm) * S_ + s0) = pk;
        } else {
          const int i2 = mm >> 1;
          const bool odd = mm & 1;
#pragma unroll
          for (int j = 0; j < 4; ++j) {
            const int row = brow + wm * 64 + mf * 16 + lg * 4 + j;
            const int b = row >> 11, s = row & (S_ - 1);
            const float val = acc[mf][nf][j];
            const float part = __shfl_xor(val, 1, 64);   // col parity == lane parity
            const float c = cost[s * 64 + i2];
            const float sn = sint[s * 64 + i2];
            float o = odd ? (part * sn + val * c) : (val * c - part * sn);
            if (t == 0) o *= SCALE_;
            const int om = odd ? (64 + i2) : i2;
            bf16* dst = (t == 1) ? kb : qb;
            dst[((size_t)(b * H_ + h) * S_ + s) * HD_ + om] = __float2bfloat16(o);
          }
        }
      }
  }
}

// ---------------- flash attention: 512 threads, 8 waves x ONE 16-row group, 16 waves/CU ----------------
// grid (16, B*H), QBLK=128 (wave w owns rows q0+w*16..+15). Same K/V dbuf staging as round 9;
// Ps is per-wave transpose scratch, split into two 32-col halves ([16][40], reused in-order)
// so total LDS stays 75776 B -> 2 blocks/CU = 16 waves/CU (vs 8 before): 4 independent
// softmax chains per SIMD hide each other's shfl/exp latency.
// Waves 0-3 skip compute on the last KV tile (their rows fully masked; barriers unconditional).
__global__ __launch_bounds__(512, 4) void k_attn(const bf16* __restrict__ qb,
                                                 const bf16* __restrict__ kb,
                                                 const bf16* __restrict__ vt,
                                                 const int* __restrict__ mask,
                                                 bf16* __restrict__ attn_b) {
  const int tid = threadIdx.x, w = tid >> 6, lane = tid & 63;
  const int lr = lane & 15, lg = lane >> 4;
  const int qt = (blockIdx.y < 16) ? ((int)gridDim.x - 1 - (int)blockIdx.x)
                                   : (int)blockIdx.x;   // complementary CU pairing
  const int q0 = qt * 128;
  const int bh = blockIdx.y;
  const int b = bh >> 4, h = bh & (H_ - 1);
  const bf16* qp = qb + (size_t)bh * S_ * HD_;
  const bf16* kp = kb + (size_t)bh * S_ * HD_;
  const bf16* vp = vt + (size_t)bh * HD_ * S_;
  __shared__ __align__(16) bf16 Ks[2][64 * 128];   // 2 x 16 KB, XOR-swizzled rows
  __shared__ __align__(16) bf16 Vs[2][128 * 64];   // 2 x 16 KB, XOR-swizzled rows
  __shared__ __align__(16) bf16 Ps[8][16][40];     // per-wave half-P scratch (1.25 KB each)

  const int qrow = q0 + w * 16 + lr;
  bf16x8 qf[4];
#pragma unroll
  for (int ks = 0; ks < 4; ++ks)
    qf[ks] = *(const bf16x8*)(qp + (size_t)qrow * HD_ + ks * 32 + lg * 8);

  float m_run[4], l_run[4];
  f32x4 oacc[8];
#pragma unroll
  for (int j = 0; j < 4; ++j) { m_run[j] = -INFINITY; l_run[j] = 0.f; }
#pragma unroll
  for (int c = 0; c < 8; ++c) oacc[c] = (f32x4)(0.f);

  // stage K[64][128] and V[128][64] (1024 16B units each; 512 threads x 2)
  auto stage = [&](int buf, int k0) {
#pragma unroll
    for (int i = 0; i < 2; ++i) {
      const int slot = i * 512 + tid;
      const int row = slot >> 4, j16 = slot & 15;
      load_lds16(kp + (size_t)(k0 + row) * HD_ + ((j16 ^ (row & 7)) * 8),
                 (char*)&Ks[buf][0] + i * 8192 + w * 1024);
    }
#pragma unroll
    for (int i = 0; i < 2; ++i) {
      const int slot = i * 512 + tid;
      const int row = slot >> 3, j8 = slot & 7;
      load_lds16(vp + (size_t)row * S_ + k0 + ((j8 ^ (row & 7)) * 8),
                 (char*)&Vs[buf][0] + i * 8192 + w * 1024);
    }
  };

  const int nt = 2 * qt + 2;
  stage(0, 0);
  asm volatile("s_waitcnt vmcnt(0)" ::: "memory");
  __syncthreads();

  int cur = 0;
  for (int it = 0; it < nt; ++it) {
    const int k0 = it * 64;
    if (it + 1 < nt) stage(cur ^ 1, k0 + 64);   // prefetch next tile (in flight across compute)

    // waves 0-3: rows q0+w*16..+15 all < q0+64 <= k0 on the last tile -> fully masked, skip
    const bool active = (it + 1 < nt) || (w >= 4);

    if (active) {
      int mk4[4];
#pragma unroll
      for (int n = 0; n < 4; ++n) mk4[n] = mask[b * S_ + k0 + n * 16 + lr];

      const bf16* ksb = &Ks[cur][0];
      const bf16* vsb = &Vs[cur][0];

      // QK^T: 16 q-rows x 64 k
      f32x4 sacc[4] = {};
      __builtin_amdgcn_s_setprio(1);
#pragma unroll
      for (int n = 0; n < 4; ++n) {
        const int krow = n * 16 + lr;
#pragma unroll
        for (int ks = 0; ks < 4; ++ks) {
          const int j16 = (ks * 4 + lg) ^ (krow & 7);
          const bf16x8 kf = *(const bf16x8*)(ksb + krow * 128 + j16 * 8);
          sacc[n] = __builtin_amdgcn_mfma_f32_16x16x32_bf16(qf[ks], kf, sacc[n], 0, 0, 0);
        }
      }
      __builtin_amdgcn_s_setprio(0);

      // mask + row max
      float mblk[4] = {-INFINITY, -INFINITY, -INFINITY, -INFINITY};
#pragma unroll
      for (int n = 0; n < 4; ++n) {
        const int kcol = k0 + n * 16 + lr;
#pragma unroll
        for (int j = 0; j < 4; ++j) {
          const int r = q0 + w * 16 + lg * 4 + j;
          float sv = sacc[n][j];
          const bool allowed = (kcol <= r) && (mk4[n] != 0 || kcol == r);
          sv = allowed ? sv : -1e9f;
          sacc[n][j] = sv;
          mblk[j] = fmaxf(mblk[j], sv);
        }
      }
#pragma unroll
      for (int xm = 1; xm < 16; xm <<= 1)
#pragma unroll
        for (int j = 0; j < 4; ++j)
          mblk[j] = fmaxf(mblk[j], __shfl_xor(mblk[j], xm, 64));

      // defer-max (T13)
      bool grow = false;
#pragma unroll
      for (int j = 0; j < 4; ++j) grow = grow || (mblk[j] > m_run[j] + 8.f);
      if (__any(grow)) {
        float alpha[4];
#pragma unroll
        for (int j = 0; j < 4; ++j) {
          const float mn = fmaxf(m_run[j], mblk[j]);
          alpha[j] = __expf(m_run[j] - mn);
          m_run[j] = mn;
          l_run[j] *= alpha[j];
        }
#pragma unroll
        for (int c = 0; c < 8; ++c)
#pragma unroll
          for (int j = 0; j < 4; ++j) oacc[c][j] *= alpha[j];
      }

      float psum[4] = {0.f, 0.f, 0.f, 0.f};
#pragma unroll
      for (int n = 0; n < 4; ++n)
#pragma unroll
        for (int j = 0; j < 4; ++j) {
          const float p = __expf(sacc[n][j] - m_run[j]);
          psum[j] += p;
          sacc[n][j] = p;
        }
#pragma unroll
      for (int xm = 1; xm < 16; xm <<= 1)
#pragma unroll
        for (int j = 0; j < 4; ++j)
          psum[j] += __shfl_xor(psum[j], xm, 64);
#pragma unroll
      for (int j = 0; j < 4; ++j) l_run[j] += psum[j];

      // PV in two 32-col halves through the per-wave half-P scratch (in-order reuse)
#pragma unroll
      for (int hh = 0; hh < 2; ++hh) {
#pragma unroll
        for (int n2 = 0; n2 < 2; ++n2)
#pragma unroll
          for (int j = 0; j < 4; ++j)
            Ps[w][lg * 4 + j][n2 * 16 + lr] = __float2bfloat16(sacc[hh * 2 + n2][j]);
        const bf16x8 pa = *(const bf16x8*)(&Ps[w][lr][lg * 8]);
        __builtin_amdgcn_s_setprio(1);
#pragma unroll
        for (int c = 0; c < 8; ++c) {
          const int vrow = c * 16 + lr;
          const int unit = (hh * 4 + lg) ^ (vrow & 7);
          const bf16x8 vf = *(const bf16x8*)(vsb + vrow * 64 + unit * 8);
          oacc[c] = __builtin_amdgcn_mfma_f32_16x16x32_bf16(pa, vf, oacc[c], 0, 0, 0);
        }
        __builtin_amdgcn_s_setprio(0);
      }
    }

    asm volatile("s_waitcnt vmcnt(0)" ::: "memory");  // next tile staged
    __syncthreads();                                   // all waves done with cur
    cur ^= 1;
  }

  // epilogue: normalize and write attn_b [B,S,H*hd] bf16
#pragma unroll
  for (int j = 0; j < 4; ++j) {
    const float inv = 1.f / l_run[j];
    const int r = q0 + w * 16 + lg * 4 + j;
#pragma unroll
    for (int c = 0; c < 8; ++c)
      attn_b[(size_t)(b * S_ + r) * D_ + h * HD_ + c * 16 + lr] =
          __float2bfloat16(oacc[c][j] * inv);
  }
}

extern "C" void kernel_launch(void* const* d_in, const int* in_sizes, int n_in,
                              void* d_out, int out_size, void* d_ws, size_t ws_size,
                              hipStream_t stream) {
  (void)in_sizes; (void)n_in; (void)out_size; (void)ws_size;
  const float* x        = (const float*)d_in[0];
  const int*   attn_mask= (const int*)d_in[1];
  const float* in_proj  = (const float*)d_in[2];
  const float* out_proj = (const float*)d_in[3];
  float* out = (float*)d_out;
  char* ws = (char*)d_ws;

  bf16*  xb    = (bf16*)(ws + 0);            // 16 MB (also attn_b later)
  bf16*  wqkvT = (bf16*)(ws + 16777216);     // 24 MB  ([3][2048][2048] = [6144][2048])
  bf16*  woT   = (bf16*)(ws + 41943040);     //  8 MB
  float* cost  = (float*)(ws + 50331648);
  float* sint  = (float*)(ws + 50855936);
  bf16*  vt    = (bf16*)(ws + 51380224);     // 16 MB
  bf16* qb = (bf16*)d_out;                   // d_out as scratch (dead before final GEMM)
  bf16* kb = (bf16*)((char*)d_out + 16777216);
  bf16* attn_b = xb;

  // allow dynamic LDS (host-side, graph-capture safe)
  static int lds_ok = 0;
  if (!lds_ok) {
    (void)hipFuncSetAttribute((const void*)k_gemm_p<0>,
                              hipFuncAttributeMaxDynamicSharedMemorySize, 73728);
    (void)hipFuncSetAttribute((const void*)k_gemm_p<1>,
                              hipFuncAttributeMaxDynamicSharedMemorySize, 49152);
    lds_ok = 1;
  }

  k_convert<<<4096, 256, 0, stream>>>(x, xb);
  k_transpose<<<dim3(32, 32, 3), 256, 0, stream>>>(in_proj, wqkvT);
  k_transpose<<<dim3(32, 32, 1), 256, 0, stream>>>(out_proj, woT);
  k_rope_tables<<<512, 256, 0, stream>>>(cost, sint);
  k_gemm_p<0><<<dim3(32, 24), 512, 73728, stream>>>(xb, wqkvT, nullptr, qb, kb, vt, cost, sint);
  k_attn<<<dim3(16, 32), 512, 0, stream>>>(qb, kb, vt, attn_mask, attn_b);
  k_gemm_p<1><<<dim3(32, 16), 512, 49152, stream>>>(attn_b, woT, out, nullptr, nullptr, nullptr,
                                                    nullptr, nullptr);
}